// Round 3
// baseline (1862.705 us; speedup 1.0000x reference)
//
#include <hip/hip_runtime.h>

typedef __bf16 bf16x8 __attribute__((ext_vector_type(8)));
typedef float f32x16 __attribute__((ext_vector_type(16)));
typedef unsigned int u32x4 __attribute__((ext_vector_type(4)));

#define NGROUP 8
#define DMODEL 256
#define DFF    1024
#define TTOT   131072
#define TGRP   (TTOT / NGROUP)   // 16384
#define MTILE  256               // tokens per block: 4 waves x 64
#define NCHUNK 32                // f-chunks of 32
// LDS (48 KB): [0,32K) gate+up frags [2*16 ks][64 lanes]x16B ; [32K,48K) down frags

__device__ __forceinline__ unsigned int f2bf(float f) {
    unsigned int x = __builtin_bit_cast(unsigned int, f);
    return (x + 0x7fffu + ((x >> 16) & 1u)) >> 16;   // RNE
}
__device__ __forceinline__ unsigned int pack2(float lo, float hi) {
    return f2bf(lo) | (f2bf(hi) << 16);
}
__device__ __forceinline__ void g2l(const void* g, void* l) {
    __builtin_amdgcn_global_load_lds(
        (const __attribute__((address_space(1))) unsigned int*)g,
        (__attribute__((address_space(3))) unsigned int*)l, 16, 0, 0);
}
#define MFMA(A, B, C) __builtin_amdgcn_mfma_f32_32x32x16_bf16( \
        __builtin_bit_cast(bf16x8, (A)), __builtin_bit_cast(bf16x8, (B)), (C), 0, 0, 0)

// ---------------- prep: all weights -> per-(group,chunk) 48KB frag blocks ----------------
// Per (g,c): fid 0..15 gate A-frag ks, 16..31 up A-frag, 32..47 down B-frag (ks2,nb)
__global__ void k_prep_w(const float* __restrict__ wg, const float* __restrict__ wu,
                         const float* __restrict__ wd, u32x4* __restrict__ out) {
    int t = blockIdx.x * 256 + threadIdx.x;   // 786432 total
    int lane = t & 63;
    int q = lane >> 5, l31 = lane & 31;
    int fg = t >> 6;
    int fid = fg % 48;
    int gc  = fg / 48;
    int c = gc & 31, g = gc >> 5;
    const float* src;
    int stride;
    if (fid < 32) {
        const float* w = (fid < 16) ? wg : wu;
        int ks = fid & 15;
        src = w + (size_t)(g * 256 + ks * 16 + q * 8) * 1024 + c * 32 + l31;
        stride = 1024;
    } else {
        int idx = fid - 32;
        int ks2 = idx >> 3, nb = idx & 7;
        src = wd + (size_t)(g * 1024 + (c * 2 + ks2) * 16 + q * 8) * 256 + nb * 32 + l31;
        stride = 256;
    }
    u32x4 v = { pack2(src[0],          src[stride]),
                pack2(src[2 * stride], src[3 * stride]),
                pack2(src[4 * stride], src[5 * stride]),
                pack2(src[6 * stride], src[7 * stride]) };
    out[t] = v;
}

// ---------------- main fused grouped-GLU ----------------
__global__ __launch_bounds__(256, 2)
void k_glu(const float* __restrict__ x,      // fp32 x row-major [T][256]
           const u32x4* __restrict__ wcomb,  // [g][c][48 frag-groups][64 lanes]
           float* __restrict__ y) {
    __shared__ u32x4 smem[3072];   // 48 KB

    const int tid  = threadIdx.x;
    const int lane = tid & 63;
    const int w    = tid >> 6;      // wave 0..3, owns token tiles 2w, 2w+1
    const int q    = lane >> 5;
    const int l31  = lane & 31;

    const int g    = blockIdx.x & 7;              // XCD-aligned group
    const int m0   = g * TGRP + (blockIdx.x >> 3) * MTILE;

    const u32x4* wcg = wcomb + (size_t)g * (NCHUNK * 3072);

    // prologue: stage chunk 0 (gate/up 32KB + down 16KB), async
    {
        const u32x4* src = wcg;
        #pragma unroll
        for (int i = 0; i < 8; ++i) {
            int off = i * 256 + w * 64;
            g2l(src + off + lane, smem + off);
        }
        #pragma unroll
        for (int i = 0; i < 4; ++i) {
            int off = 2048 + i * 256 + w * 64;
            g2l(src + off + lane, smem + off);
        }
    }

    // x fp32 -> bf16 A/B fragments, 2 token tiles, register-resident
    u32x4 xf[2][16];
    #pragma unroll
    for (int t = 0; t < 2; ++t) {
        const float* rowp = x + (size_t)(m0 + (w * 2 + t) * 32 + l31) * DMODEL + q * 8;
        #pragma unroll
        for (int ks = 0; ks < 16; ++ks) {
            float4 a = *(const float4*)(rowp + ks * 16);
            float4 b = *(const float4*)(rowp + ks * 16 + 4);
            u32x4 v = { pack2(a.x, a.y), pack2(a.z, a.w), pack2(b.x, b.y), pack2(b.z, b.w) };
            xf[t][ks] = v;
        }
    }

    f32x16 acc[2][8];
    #pragma unroll
    for (int t = 0; t < 2; ++t)
        #pragma unroll
        for (int nb = 0; nb < 8; ++nb)
            #pragma unroll
            for (int i = 0; i < 16; ++i) acc[t][nb][i] = 0.0f;

    __syncthreads();   // chunk-0 stage visible

    for (int c = 0; c < NCHUNK; ++c) {
        // ---- GEMM1: z^T (32f x 2x32tok); weight frag read once, used twice
        f32x16 zg[2], zu[2];
        #pragma unroll
        for (int t = 0; t < 2; ++t)
            #pragma unroll
            for (int i = 0; i < 16; ++i) { zg[t][i] = 0.0f; zu[t][i] = 0.0f; }
        #pragma unroll
        for (int ks = 0; ks < 16; ++ks) {
            const u32x4 a1 = smem[ks * 64 + lane];          // gate
            const u32x4 a2 = smem[1024 + ks * 64 + lane];   // up
            zg[0] = MFMA(a1, xf[0][ks], zg[0]);
            zg[1] = MFMA(a1, xf[1][ks], zg[1]);
            zu[0] = MFMA(a2, xf[0][ks], zu[0]);
            zu[1] = MFMA(a2, xf[1][ks], zu[1]);
        }

        // ---- act: h = silu(zg)*zu -> packed bf16 pairs (C layout)
        unsigned int pv[2][8];
        #pragma unroll
        for (int t = 0; t < 2; ++t) {
            #pragma unroll
            for (int a = 0; a < 4; ++a) {
                const float g0 = zg[t][4 * a + 0], g1 = zg[t][4 * a + 1];
                const float g2 = zg[t][4 * a + 2], g3 = zg[t][4 * a + 3];
                const float h0 = g0 / (1.0f + __expf(-g0)) * zu[t][4 * a + 0];
                const float h1 = g1 / (1.0f + __expf(-g1)) * zu[t][4 * a + 1];
                const float h2 = g2 / (1.0f + __expf(-g2)) * zu[t][4 * a + 2];
                const float h3 = g3 / (1.0f + __expf(-g3)) * zu[t][4 * a + 3];
                pv[t][2 * a]     = pack2(h0, h1);
                pv[t][2 * a + 1] = pack2(h2, h3);
            }
        }

        // ---- C-layout -> A-layout: exchange with lane^32 partner (4 shfl/tile)
        // q=0 lane needs partner pv[0,1,4,5]; q=1 lane needs partner pv[2,3,6,7]
        u32x4 hf[2][2];
        #pragma unroll
        for (int t = 0; t < 2; ++t) {
            const int s0[4] = {2, 3, 6, 7};   // q=0 sends
            const int s1[4] = {0, 1, 4, 5};   // q=1 sends
            unsigned int rr[4];
            #pragma unroll
            for (int i = 0; i < 4; ++i) {
                unsigned int s = q ? pv[t][s1[i]] : pv[t][s0[i]];
                rr[i] = (unsigned int)__shfl_xor((int)s, 32, 64);
            }
            u32x4 h0 = { q ? rr[0] : pv[t][0], q ? rr[1] : pv[t][1],
                         q ? pv[t][2] : rr[0], q ? pv[t][3] : rr[1] };
            u32x4 h1 = { q ? rr[2] : pv[t][4], q ? rr[3] : pv[t][5],
                         q ? pv[t][6] : rr[2], q ? pv[t][7] : rr[3] };
            hf[t][0] = h0;
            hf[t][1] = h1;
        }

        __syncthreads();   // B1: gate/up(c) consumed by all; down(c) visible
        if (c + 1 < NCHUNK) {   // prefetch gate/up(c+1), overlaps GEMM2
            const u32x4* src = wcg + (size_t)(c + 1) * 3072;
            #pragma unroll
            for (int i = 0; i < 8; ++i) {
                int off = i * 256 + w * 64;
                g2l(src + off + lane, smem + off);
            }
        }

        // ---- GEMM2: acc += h(2x32tok x 32f) * Wd(32f x 256); Wd frag used twice
        #pragma unroll
        for (int ks2 = 0; ks2 < 2; ++ks2) {
            #pragma unroll
            for (int nb = 0; nb < 8; ++nb) {
                const u32x4 bd = smem[2048 + (ks2 * 8 + nb) * 64 + lane];
                acc[0][nb] = MFMA(hf[0][ks2], bd, acc[0][nb]);
                acc[1][nb] = MFMA(hf[1][ks2], bd, acc[1][nb]);
            }
        }

        __syncthreads();   // B2: down(c) consumed; gate/up(c+1) visible
        if (c + 1 < NCHUNK) {   // prefetch down(c+1), overlaps next GEMM1
            const u32x4* src = wcg + (size_t)(c + 1) * 3072;
            #pragma unroll
            for (int i = 0; i < 4; ++i) {
                int off = 2048 + i * 256 + w * 64;
                g2l(src + off + lane, smem + off);
            }
        }
    }

    // epilogue: C layout -> y fp32
    #pragma unroll
    for (int t = 0; t < 2; ++t) {
        float* yp = y + (size_t)(m0 + (w * 2 + t) * 32) * DMODEL;
        #pragma unroll
        for (int nb = 0; nb < 8; ++nb) {
            const int col = nb * 32 + l31;
            #pragma unroll
            for (int r = 0; r < 16; ++r) {
                const int row = (r & 3) + (r >> 2) * 8 + q * 4;
                yp[(size_t)row * DMODEL + col] = acc[t][nb][r];
            }
        }
    }
}

extern "C" void kernel_launch(void* const* d_in, const int* in_sizes, int n_in,
                              void* d_out, int out_size, void* d_ws, size_t ws_size,
                              hipStream_t stream) {
    const float* x  = (const float*)d_in[0];
    const float* wg = (const float*)d_in[1];
    const float* wu = (const float*)d_in[2];
    const float* wd = (const float*)d_in[3];
    float* y = (float*)d_out;

    u32x4* wcomb = (u32x4*)d_ws;   // 8*32*48*64 = 786432 u32x4 = 12 MB

    k_prep_w<<<dim3(3072), dim3(256), 0, stream>>>(wg, wu, wd, wcomb);
    k_glu<<<dim3(512), dim3(256), 0, stream>>>(x, wcomb, y);
}